// Round 4
// baseline (306.595 us; speedup 1.0000x reference)
//
#include <hip/hip_runtime.h>
#include <cstdint>

#define N_ANCH 8400
#define CBLK 132              // ceil(8400/64)
#define SCORE_THR 0.5f

typedef unsigned long long u64;
typedef unsigned int u32;
typedef unsigned short u16;

// Sort key: ascending sort == (valid score descending, then index ascending,
// invalid last by index ascending) — exactly matches
// argsort(-where(valid, s, -inf)) with stable ties.
__device__ __forceinline__ u64 sort_key(float s, int idx) {
  u32 k32 = (s >= SCORE_THR) ? ~__float_as_uint(s) : 0xFFFFFFFFu;
  return ((u64)k32 << 32) | (u32)idx;
}

__device__ __forceinline__ u64 readlane_u64(u32 lo, u32 hi, int l) {
  u32 rlo = (u32)__builtin_amdgcn_readlane((int)lo, l);
  u32 rhi = (u32)__builtin_amdgcn_readlane((int)hi, l);
  return ((u64)rhi << 32) | rlo;
}

// One 64-lane wave per anchor: rank = #{keys smaller}, then scatter
// decoded box + score into sorted position.
__global__ void __launch_bounds__(256) rank_kernel(const float* __restrict__ raw,
                                                   float4* __restrict__ sbox,
                                                   float* __restrict__ sscore) {
  #pragma clang fp contract(off)
  int tid = blockIdx.x * 256 + threadIdx.x;
  int row = tid >> 6, lane = tid & 63;
  if (row >= N_ANCH) return;
  float si = raw[4 * N_ANCH + row];
  u64 ki = sort_key(si, row);
  int cnt = 0;
  for (int j = lane; j < N_ANCH; j += 64) {
    float sj = raw[4 * N_ANCH + j];
    cnt += (sort_key(sj, j) < ki) ? 1 : 0;
  }
  #pragma unroll
  for (int d = 1; d < 64; d <<= 1) cnt += __shfl_xor(cnt, d, 64);
  if (lane == 0) {
    float cx = raw[row], cy = raw[N_ANCH + row];
    float w = raw[2 * N_ANCH + row], h = raw[3 * N_ANCH + row];
    float hw = w * 0.5f, hh = h * 0.5f;
    sbox[cnt] = make_float4(cx - hw, cy - hh, cx + hw, cy + hh);
    sscore[cnt] = si;
  }
}

// Suppression bitmask over sorted boxes. 256 threads = 256 rows x 64 cols
// per block; grid (CBLK, 33). mask[i*CBLK+cb] bit jj set iff j=cb*64+jj has
// j>i, j<N, iou(i,j) > 0.5. Skips tiles below the diagonal and tiles with
// all-invalid rows/cols (validity is a prefix in sorted order).
__global__ void __launch_bounds__(256) mask_kernel(const float4* __restrict__ sbox,
                                                   const float* __restrict__ sscore,
                                                   u64* __restrict__ mask) {
  #pragma clang fp contract(off)
  int cb = blockIdx.x;
  int i0 = blockIdx.y * 256;
  if (cb * 64 + 63 < i0) return;
  if (!(sscore[i0] >= SCORE_THR)) return;
  if (!(sscore[cb * 64] >= SCORE_THR)) return;
  int t = threadIdx.x;
  __shared__ float4 cbox[64];
  __shared__ float carea[64];
  int j0 = cb * 64;
  if (t < 64) {
    int j = j0 + t;
    float4 bj = (j < N_ANCH) ? sbox[j] : make_float4(0.f, 0.f, 0.f, 0.f);
    cbox[t] = bj;
    carea[t] = (bj.z - bj.x) * (bj.w - bj.y);
  }
  __syncthreads();
  int i = i0 + t;
  if (i >= N_ANCH || i >= (cb + 1) * 64) return;
  float4 bi = sbox[i];
  float ai = (bi.z - bi.x) * (bi.w - bi.y);
  u64 word = 0;
  for (int jj = 0; jj < 64; ++jj) {
    int jg = j0 + jj;
    if (jg <= i || jg >= N_ANCH) continue;
    float4 bb = cbox[jj];
    float ltx = fmaxf(bi.x, bb.x), lty = fmaxf(bi.y, bb.y);
    float rbx = fminf(bi.z, bb.z), rby = fminf(bi.w, bb.w);
    float wx = fmaxf(rbx - ltx, 0.f), wy = fmaxf(rby - lty, 0.f);
    float inter = wx * wy;
    float uni = (ai + carea[jj]) - inter;      // same op order as reference
    float iou = inter / fmaxf(uni, 1e-9f);     // IEEE div, matches numpy
    if (iou > 0.5f) word |= (1ull << jj);
  }
  mask[(u64)i * CBLK + cb] = word;
}

// Single WAVE (64 threads), wave-synchronous.
//  - n_valid via 2-round sorted-prefix probe
//  - greedy scan: scalar chain (s_ff1 + v_readlane + s_andn2), ~15-20 cy/kept
//  - propagation: incremental LDS removed[]; lane L owns columns b+1+L
//    (+64,+128); fixed 64-unrolled coalesced gather of kept rows' words
//  - diagonal mask words prefetched one block ahead
__global__ void __launch_bounds__(64) nms_kernel(const float4* __restrict__ sbox,
                                                 const float* __restrict__ sscore,
                                                 const u64* __restrict__ mask,
                                                 float* __restrict__ out) {
  __shared__ u64 keepw[CBLK];
  __shared__ u64 removed[CBLK];
  int lane = threadIdx.x;

  // ---- n_valid via 2-round probe (scores sorted desc => validity is prefix)
  float s0 = sscore[lane * 132];                 // 63*132 = 8316 < 8400
  u64 b0 = __ballot(s0 >= SCORE_THR);
  int cnt1 = (int)__popcll(b0);
  int n_valid = 0;
  if (cnt1 > 0) {
    int a = (cnt1 - 1) * 132 + 1;                // rows < a known valid
    int i1 = a + 3 * lane;
    float t1 = (i1 + 0 < N_ANCH) ? sscore[i1 + 0] : -1.f;
    float t2 = (i1 + 1 < N_ANCH) ? sscore[i1 + 1] : -1.f;
    float t3 = (i1 + 2 < N_ANCH) ? sscore[i1 + 2] : -1.f;
    u64 q1 = __ballot(t1 >= SCORE_THR);
    u64 q2 = __ballot(t2 >= SCORE_THR);
    u64 q3 = __ballot(t3 >= SCORE_THR);
    n_valid = a + (int)__popcll(q1) + (int)__popcll(q2) + (int)__popcll(q3);
  }
  int VB = (n_valid + 63) >> 6;                  // number of valid blocks

  for (int b = lane; b < CBLK; b += 64) { keepw[b] = 0; removed[b] = 0; }
  __syncthreads();

  // prefetch diagonal words for block 0
  u64 mw_pref = 0;
  if (VB > 0) mw_pref = mask[(u64)lane * CBLK + 0];

  for (int b = 0; b < VB; ++b) {
    u64 mw = mw_pref;
    if (b + 1 < VB) {                            // prefetch next diagonal early
      int rn = (b + 1) * 64 + lane;
      rn = (rn < N_ANCH) ? rn : (N_ANCH - 1);    // clamp (lanes never consumed)
      mw_pref = mask[(u64)rn * CBLK + (b + 1)];
    }
    int rem = n_valid - b * 64;                  // >= 1
    u64 vmask = (rem >= 64) ? ~0ull : ((1ull << rem) - 1ull);
    u64 act = vmask & ~removed[b];

    // ---- greedy scan, scalar chain; record kept row l for kept-index == lane
    u32 mw_lo = (u32)mw, mw_hi = (u32)(mw >> 32);
    u64 kw = 0;
    u32 rowA = 0;                                // clamp row for unused lanes
    int nkw = 0;
    u64 a = act;
    while (a) {
      int l = (int)__builtin_ctzll(a);
      kw |= (1ull << l);
      u64 ml = readlane_u64(mw_lo, mw_hi, l);
      a &= ~(1ull << l) & ~ml;                   // ml has only bits > l
      rowA = (lane == nkw) ? (u32)(b * 64 + l) : rowA;
      ++nkw;
    }
    if (lane == 0) keepw[b] = kw;

    // ---- propagate to future columns; lane owns c, c+64, c+128
    if (nkw) {
      #pragma unroll
      for (int s = 0; s < 3; ++s) {
        int c = b + 1 + lane + s * 64;
        if (c < VB) {
          u64 acc = 0;
          #pragma unroll
          for (int i = 0; i < 64; ++i) {
            u32 ri = (u32)__builtin_amdgcn_readlane((int)rowA, i);
            u64 v = mask[(u64)ri * CBLK + c];
            acc |= (i < nkw) ? v : 0ull;         // uniform select
          }
          removed[c] |= acc;                     // exclusive per lane
        }
      }
    }
    __syncthreads();                             // order LDS writes vs next read
  }
  __syncthreads();

  // ---- fused masked output
  for (int r2 = lane; r2 < N_ANCH; r2 += 64) {
    u64 kv = keepw[r2 >> 6];
    bool kp = (kv >> (r2 & 63)) & 1ull;
    float4 b4 = sbox[r2];
    float sc = sscore[r2];
    float* o = out + r2 * 5;
    o[0] = kp ? b4.x : 0.f;
    o[1] = kp ? b4.y : 0.f;
    o[2] = kp ? b4.z : 0.f;
    o[3] = kp ? b4.w : 0.f;
    o[4] = kp ? sc : 0.f;
  }
}

extern "C" void kernel_launch(void* const* d_in, const int* in_sizes, int n_in,
                              void* d_out, int out_size, void* d_ws, size_t ws_size,
                              hipStream_t stream) {
  const float* raw = (const float*)d_in[0];
  float* out = (float*)d_out;
  char* ws = (char*)d_ws;
  // ws layout: sbox (8448*16 B) | sscore (8448*4 B) | mask (8400*132*8 B) ≈ 9.04 MB
  float4* sbox = (float4*)ws;
  float* sscore = (float*)(ws + 8448 * 16);
  u64* mask = (u64*)(ws + 8448 * 16 + 8448 * 4);

  rank_kernel<<<2100, 256, 0, stream>>>(raw, sbox, sscore);
  mask_kernel<<<dim3(CBLK, 33), 256, 0, stream>>>(sbox, sscore, mask);
  nms_kernel<<<1, 64, 0, stream>>>(sbox, sscore, mask, out);
}

// Round 5
// 284.342 us; speedup vs baseline: 1.0783x; 1.0783x over previous
//
#include <hip/hip_runtime.h>
#include <cstdint>

#define N_ANCH 8400
#define CBLK 132              // ceil(8400/64)
#define SCORE_THR 0.5f

typedef unsigned long long u64;
typedef unsigned int u32;
typedef unsigned short u16;

// Sort key: ascending sort == (valid score descending, then index ascending,
// invalid last by index ascending) — exactly matches
// argsort(-where(valid, s, -inf)) with stable ties.
__device__ __forceinline__ u64 sort_key(float s, int idx) {
  u32 k32 = (s >= SCORE_THR) ? ~__float_as_uint(s) : 0xFFFFFFFFu;
  return ((u64)k32 << 32) | (u32)idx;
}

__device__ __forceinline__ u64 readlane_u64(u32 lo, u32 hi, int l) {
  u32 rlo = (u32)__builtin_amdgcn_readlane((int)lo, l);
  u32 rhi = (u32)__builtin_amdgcn_readlane((int)hi, l);
  return ((u64)rhi << 32) | rlo;
}

// One 64-lane wave per anchor: rank = #{keys smaller}, then scatter
// decoded box + score into sorted position.
__global__ void __launch_bounds__(256) rank_kernel(const float* __restrict__ raw,
                                                   float4* __restrict__ sbox,
                                                   float* __restrict__ sscore) {
  #pragma clang fp contract(off)
  int tid = blockIdx.x * 256 + threadIdx.x;
  int row = tid >> 6, lane = tid & 63;
  if (row >= N_ANCH) return;
  float si = raw[4 * N_ANCH + row];
  u64 ki = sort_key(si, row);
  int cnt = 0;
  for (int j = lane; j < N_ANCH; j += 64) {
    float sj = raw[4 * N_ANCH + j];
    cnt += (sort_key(sj, j) < ki) ? 1 : 0;
  }
  #pragma unroll
  for (int d = 1; d < 64; d <<= 1) cnt += __shfl_xor(cnt, d, 64);
  if (lane == 0) {
    float cx = raw[row], cy = raw[N_ANCH + row];
    float w = raw[2 * N_ANCH + row], h = raw[3 * N_ANCH + row];
    float hw = w * 0.5f, hh = h * 0.5f;
    sbox[cnt] = make_float4(cx - hw, cy - hh, cx + hw, cy + hh);
    sscore[cnt] = si;
  }
}

// Suppression bitmask over sorted boxes. 256 threads = 256 rows x 64 cols
// per block; grid (CBLK, 33). mask[i*CBLK+cb] bit jj set iff j=cb*64+jj has
// j>i, j<N, iou(i,j) > 0.5. Skips tiles below the diagonal and tiles with
// all-invalid rows/cols (validity is a prefix in sorted order).
__global__ void __launch_bounds__(256) mask_kernel(const float4* __restrict__ sbox,
                                                   const float* __restrict__ sscore,
                                                   u64* __restrict__ mask) {
  #pragma clang fp contract(off)
  int cb = blockIdx.x;
  int i0 = blockIdx.y * 256;
  if (cb * 64 + 63 < i0) return;
  if (!(sscore[i0] >= SCORE_THR)) return;
  if (!(sscore[cb * 64] >= SCORE_THR)) return;
  int t = threadIdx.x;
  __shared__ float4 cbox[64];
  __shared__ float carea[64];
  int j0 = cb * 64;
  if (t < 64) {
    int j = j0 + t;
    float4 bj = (j < N_ANCH) ? sbox[j] : make_float4(0.f, 0.f, 0.f, 0.f);
    cbox[t] = bj;
    carea[t] = (bj.z - bj.x) * (bj.w - bj.y);
  }
  __syncthreads();
  int i = i0 + t;
  if (i >= N_ANCH || i >= (cb + 1) * 64) return;
  float4 bi = sbox[i];
  float ai = (bi.z - bi.x) * (bi.w - bi.y);
  u64 word = 0;
  for (int jj = 0; jj < 64; ++jj) {
    int jg = j0 + jj;
    if (jg <= i || jg >= N_ANCH) continue;
    float4 bb = cbox[jj];
    float ltx = fmaxf(bi.x, bb.x), lty = fmaxf(bi.y, bb.y);
    float rbx = fminf(bi.z, bb.z), rby = fminf(bi.w, bb.w);
    float wx = fmaxf(rbx - ltx, 0.f), wy = fmaxf(rby - lty, 0.f);
    float inter = wx * wy;
    float uni = (ai + carea[jj]) - inter;      // same op order as reference
    float iou = inter / fmaxf(uni, 1e-9f);     // IEEE div, matches numpy
    if (iou > 0.5f) word |= (1ull << jj);
  }
  mask[(u64)i * CBLK + cb] = word;
}

// Single WAVE (64 threads), wave-synchronous, software-pipelined:
//  per block b: (1) issue 64 COALESCED propagate loads (row-major mask:
//  lane L reads column b+1+L of every row in block b — addresses independent
//  of the scan result) + diagonal prefetch for b+1; (2) scalar greedy scan
//  (s_ff1 + v_readlane chain) overlapping the load latency; (3) AND each
//  row's word with its keep bit, OR-reduce, one exclusive LDS RMW per lane.
__global__ void __launch_bounds__(64) nms_kernel(const float4* __restrict__ sbox,
                                                 const float* __restrict__ sscore,
                                                 const u64* __restrict__ mask,
                                                 float* __restrict__ out) {
  __shared__ u64 keepw[CBLK];
  __shared__ u64 removed[CBLK];
  int lane = threadIdx.x;

  // ---- n_valid via 2-round probe (scores sorted desc => validity is prefix)
  float s0 = sscore[lane * 132];                 // 63*132 = 8316 < 8400
  u64 b0 = __ballot(s0 >= SCORE_THR);
  int cnt1 = (int)__popcll(b0);
  int n_valid = 0;
  if (cnt1 > 0) {
    int a = (cnt1 - 1) * 132 + 1;                // rows < a known valid
    int i1 = a + 3 * lane;
    float t1 = (i1 + 0 < N_ANCH) ? sscore[i1 + 0] : -1.f;
    float t2 = (i1 + 1 < N_ANCH) ? sscore[i1 + 1] : -1.f;
    float t3 = (i1 + 2 < N_ANCH) ? sscore[i1 + 2] : -1.f;
    u64 q1 = __ballot(t1 >= SCORE_THR);
    u64 q2 = __ballot(t2 >= SCORE_THR);
    u64 q3 = __ballot(t3 >= SCORE_THR);
    n_valid = a + (int)__popcll(q1) + (int)__popcll(q2) + (int)__popcll(q3);
  }
  int VB = (n_valid + 63) >> 6;                  // number of valid 64-blocks

  for (int b = lane; b < CBLK; b += 64) { keepw[b] = 0; removed[b] = 0; }
  __syncthreads();

  // prefetch diagonal words for block 0 (row = lane, col-block 0)
  u64 mw_pref = (VB > 0) ? mask[(u64)lane * CBLK] : 0;

  for (int b = 0; b < VB; ++b) {
    // only the (already-arrived) diagonal prefetch is outstanding: free drain,
    // guarantees the compiler never waits on the loads we are about to issue
    __builtin_amdgcn_s_waitcnt(0x0F70);          // vmcnt(0) only
    u64 mw = mw_pref;

    int ncols = VB - 1 - b;                      // future columns b+1..VB-1
    // ---- (1) issue coalesced propagate loads BEFORE the scan
    u64 v[64];
    const u64* base = mask + (u64)(b * 64) * CBLK + (b + 1) + lane;
    if (ncols > 0) {
      #pragma unroll
      for (int i = 0; i < 64; ++i) v[i] = base[(u64)i * CBLK];
    }
    if (b + 1 < VB) {                            // diagonal prefetch for b+1
      int rn = (b + 1) * 64 + lane;
      rn = (rn < N_ANCH) ? rn : (N_ANCH - 1);
      mw_pref = mask[(u64)rn * CBLK + (b + 1)];
    }

    // ---- (2) scalar greedy scan (SALU chain, overlaps load latency)
    int rem = n_valid - b * 64;                  // >= 1
    u64 vmask = (rem >= 64) ? ~0ull : ((1ull << rem) - 1ull);
    u64 actv = vmask & ~removed[b];
    u32 act_lo = (u32)__builtin_amdgcn_readfirstlane((int)(u32)actv);
    u32 act_hi = (u32)__builtin_amdgcn_readfirstlane((int)(u32)(actv >> 32));
    u64 a = ((u64)act_hi << 32) | act_lo;
    u32 mw_lo = (u32)mw, mw_hi = (u32)(mw >> 32);
    u64 kw = 0;
    while (a) {
      int l = (int)__builtin_ctzll(a);
      kw |= (1ull << l);
      u64 ml = readlane_u64(mw_lo, mw_hi, l);
      a &= ~(1ull << l) & ~ml;                   // ml has only bits > l
    }
    if (lane == 0) keepw[b] = kw;

    // ---- (3) masked OR-reduce + exclusive LDS update (seg 0: col b+1+lane)
    if (ncols > 0) {
      u64 acc = 0;
      #pragma unroll
      for (int i = 0; i < 64; ++i) {
        u64 sm = (u64)0 - ((kw >> i) & 1ull);    // uniform keep mask for row i
        acc |= v[i] & sm;
      }
      int c = b + 1 + lane;
      if (c < VB) removed[c] |= acc;
      // rare extra segments (only when > 64 future columns remain)
      int nseg = (ncols + 63) >> 6;
      for (int s = 1; s < nseg; ++s) {
        u64 acc2 = 0;
        #pragma unroll
        for (int i = 0; i < 64; ++i) {
          u64 sm = (u64)0 - ((kw >> i) & 1ull);
          acc2 |= base[(u64)i * CBLK + s * 64] & sm;
        }
        int c2 = b + 1 + lane + s * 64;
        if (c2 < VB) removed[c2] |= acc2;
      }
    }
  }
  __syncthreads();

  // ---- fused masked output
  for (int r2 = lane; r2 < N_ANCH; r2 += 64) {
    u64 kv = keepw[r2 >> 6];
    bool kp = (kv >> (r2 & 63)) & 1ull;
    float4 b4 = sbox[r2];
    float sc = sscore[r2];
    float* o = out + r2 * 5;
    o[0] = kp ? b4.x : 0.f;
    o[1] = kp ? b4.y : 0.f;
    o[2] = kp ? b4.z : 0.f;
    o[3] = kp ? b4.w : 0.f;
    o[4] = kp ? sc : 0.f;
  }
}

extern "C" void kernel_launch(void* const* d_in, const int* in_sizes, int n_in,
                              void* d_out, int out_size, void* d_ws, size_t ws_size,
                              hipStream_t stream) {
  const float* raw = (const float*)d_in[0];
  float* out = (float*)d_out;
  char* ws = (char*)d_ws;
  // ws layout: sbox (8448*16 B) | sscore (8448*4 B) | mask (8400*132*8 B) ≈ 9.04 MB
  float4* sbox = (float4*)ws;
  float* sscore = (float*)(ws + 8448 * 16);
  u64* mask = (u64*)(ws + 8448 * 16 + 8448 * 4);

  rank_kernel<<<2100, 256, 0, stream>>>(raw, sbox, sscore);
  mask_kernel<<<dim3(CBLK, 33), 256, 0, stream>>>(sbox, sscore, mask);
  nms_kernel<<<1, 64, 0, stream>>>(sbox, sscore, mask, out);
}

// Round 7
// 269.065 us; speedup vs baseline: 1.1395x; 1.0568x over previous
//
#include <hip/hip_runtime.h>
#include <cstdint>

#define N_ANCH 8400
#define CBLK 132              // ceil(8400/64)
#define SCORE_THR 0.5f

typedef unsigned long long u64;
typedef unsigned int u32;

// Sort key: ascending sort == (valid score descending, then index ascending,
// invalid last by index ascending) — exactly matches
// argsort(-where(valid, s, -inf)) with stable ties.
__device__ __forceinline__ u64 sort_key(float s, int idx) {
  u32 k32 = (s >= SCORE_THR) ? ~__float_as_uint(s) : 0xFFFFFFFFu;
  return ((u64)k32 << 32) | (u32)idx;
}

__device__ __forceinline__ u64 readlane_u64(u64 v, int l) {
  u32 rlo = (u32)__builtin_amdgcn_readlane((int)(u32)v, l);
  u32 rhi = (u32)__builtin_amdgcn_readlane((int)(u32)(v >> 32), l);
  return ((u64)rhi << 32) | rlo;
}

// One 64-lane wave per anchor: rank = #{keys smaller}, then scatter
// decoded box + score into sorted position.
__global__ void __launch_bounds__(256) rank_kernel(const float* __restrict__ raw,
                                                   float4* __restrict__ sbox,
                                                   float* __restrict__ sscore) {
  #pragma clang fp contract(off)
  int tid = blockIdx.x * 256 + threadIdx.x;
  int row = tid >> 6, lane = tid & 63;
  if (row >= N_ANCH) return;
  float si = raw[4 * N_ANCH + row];
  u64 ki = sort_key(si, row);
  int cnt = 0;
  for (int j = lane; j < N_ANCH; j += 64) {
    float sj = raw[4 * N_ANCH + j];
    cnt += (sort_key(sj, j) < ki) ? 1 : 0;
  }
  #pragma unroll
  for (int d = 1; d < 64; d <<= 1) cnt += __shfl_xor(cnt, d, 64);
  if (lane == 0) {
    float cx = raw[row], cy = raw[N_ANCH + row];
    float w = raw[2 * N_ANCH + row], h = raw[3 * N_ANCH + row];
    float hw = w * 0.5f, hh = h * 0.5f;
    sbox[cnt] = make_float4(cx - hw, cy - hh, cx + hw, cy + hh);
    sscore[cnt] = si;
  }
}

// Suppression bitmask over sorted boxes. 256 threads = 256 rows x 64 cols
// per block; grid (CBLK, 33). mask[i*CBLK+cb] bit jj set iff j=cb*64+jj has
// j>i, j<N, iou(i,j) > 0.5. Skips tiles below the diagonal and tiles with
// all-invalid rows/cols (validity is a prefix in sorted order).
__global__ void __launch_bounds__(256) mask_kernel(const float4* __restrict__ sbox,
                                                   const float* __restrict__ sscore,
                                                   u64* __restrict__ mask) {
  #pragma clang fp contract(off)
  int cb = blockIdx.x;
  int i0 = blockIdx.y * 256;
  if (cb * 64 + 63 < i0) return;
  if (!(sscore[i0] >= SCORE_THR)) return;
  if (!(sscore[cb * 64] >= SCORE_THR)) return;
  int t = threadIdx.x;
  __shared__ float4 cbox[64];
  __shared__ float carea[64];
  int j0 = cb * 64;
  if (t < 64) {
    int j = j0 + t;
    float4 bj = (j < N_ANCH) ? sbox[j] : make_float4(0.f, 0.f, 0.f, 0.f);
    cbox[t] = bj;
    carea[t] = (bj.z - bj.x) * (bj.w - bj.y);
  }
  __syncthreads();
  int i = i0 + t;
  if (i >= N_ANCH || i >= (cb + 1) * 64) return;
  float4 bi = sbox[i];
  float ai = (bi.z - bi.x) * (bi.w - bi.y);
  u64 word = 0;
  for (int jj = 0; jj < 64; ++jj) {
    int jg = j0 + jj;
    if (jg <= i || jg >= N_ANCH) continue;
    float4 bb = cbox[jj];
    float ltx = fmaxf(bi.x, bb.x), lty = fmaxf(bi.y, bb.y);
    float rbx = fminf(bi.z, bb.z), rby = fminf(bi.w, bb.w);
    float wx = fmaxf(rbx - ltx, 0.f), wy = fmaxf(rby - lty, 0.f);
    float inter = wx * wy;
    float uni = (ai + carea[jj]) - inter;      // same op order as reference
    float iou = inter / fmaxf(uni, 1e-9f);     // IEEE div, matches numpy
    if (iou > 0.5f) word |= (1ull << jj);
  }
  mask[(u64)i * CBLK + cb] = word;
}

// Single WAVE, __launch_bounds__(64,1) => full VGPR budget.
// 3-tier tile schedule: at iteration t, columns [t+1, t+64] receive the kept
// rows of blocks t (tier A, ping-pong pipelined), t-64 (tier B, slow path),
// t-128 (tier C, slow path). Column c thus accumulates every block in
// [c-192, c-1] => complete for VB <= 192 (max here: 132).
// 'removed' and keep-history live in lane-indexed registers (col/block
// c owned by lane c&63, segment c>>6).
__global__ void __launch_bounds__(64, 1) nms_kernel(const float4* __restrict__ sbox,
                                                    const float* __restrict__ sscore,
                                                    const u64* __restrict__ mask,
                                                    float* __restrict__ out) {
  __shared__ u64 keepw[CBLK];
  int lane = threadIdx.x;

  // ---- n_valid via 2-round probe (scores sorted desc => validity is prefix)
  float s0 = sscore[lane * 132];                 // 63*132 = 8316 < 8400
  u64 b0 = __ballot(s0 >= SCORE_THR);
  int cnt1 = (int)__popcll(b0);
  int n_valid = 0;
  if (cnt1 > 0) {
    int a = (cnt1 - 1) * 132 + 1;                // rows < a known valid
    int i1 = a + 3 * lane;
    float t1 = (i1 + 0 < N_ANCH) ? sscore[i1 + 0] : -1.f;
    float t2 = (i1 + 1 < N_ANCH) ? sscore[i1 + 1] : -1.f;
    float t3 = (i1 + 2 < N_ANCH) ? sscore[i1 + 2] : -1.f;
    u64 q1 = __ballot(t1 >= SCORE_THR);
    u64 q2 = __ballot(t2 >= SCORE_THR);
    u64 q3 = __ballot(t3 >= SCORE_THR);
    n_valid = a + (int)__popcll(q1) + (int)__popcll(q2) + (int)__popcll(q3);
  }
  int VB = (n_valid + 63) >> 6;                  // number of valid 64-blocks

  for (int b = lane; b < CBLK; b += 64) keepw[b] = 0;

  u64 rem0 = 0, rem1 = 0, rem2 = 0;              // removed words (reg-resident)
  u64 kh0 = 0, kh1 = 0, kh2 = 0;                 // keep-word history
  u64 vbuf0[64], vbuf1[64];                      // tier-A ping-pong buffers

  // helpers (fully inlined; indices constant after unroll => stay in regs)
  auto issue_tile = [&](u64* vb, int tt) {       // tile consumed at iter tt
    int cc = tt + 1 + (int)((u32)(lane - (tt + 1)) & 63u);
    cc = (cc < CBLK) ? cc : (CBLK - 1);
    const u64* bp = mask + (u64)(tt * 64) * CBLK + cc;
    #pragma unroll
    for (int i = 0; i < 64; ++i) vb[i] = bp[(u64)i * CBLK];
  };
  auto consume_tile = [&](const u64* vb, u64 kws) {
    u64 r = 0;
    #pragma unroll
    for (int i = 0; i < 64; ++i) {
      u64 sm = (u64)0 - ((kws >> i) & 1ull);     // scalar keep mask for row i
      r |= vb[i] & sm;
    }
    return r;
  };

  // prologue: diag words for block 0; tier-A tile for t=0
  u64 mw_pref = (VB > 0) ? mask[(u64)lane * CBLK] : 0;
  if (VB >= 2) issue_tile(vbuf0, 0);

  for (int t = 0; t < VB; ++t) {
    // ---- removed word for this block (register readlane)
    int seg = t >> 6, owner = t & 63;
    u64 remb = readlane_u64(seg == 0 ? rem0 : (seg == 1 ? rem1 : rem2), owner);
    int remn = n_valid - t * 64;                 // >= 1
    u64 vmask = (remn >= 64) ? ~0ull : ((1ull << remn) - 1ull);
    u64 act = vmask & ~remb;

    // ---- scan (ballot fast path; serial steps == kept suppressor rows)
    u64 mw = mw_pref;
    u64 sup = __ballot((((act >> lane) & 1ull) != 0ull) && (mw != 0ull));
    u64 a = act, kw = 0;
    while (a) {
      u64 as = a & sup;
      if (as == 0ull) { kw |= a; break; }
      int f = (int)__builtin_ctzll(as);
      u64 below = a & ((1ull << f) - 1ull);
      kw |= below | (1ull << f);
      u64 ml = readlane_u64(mw, f);
      a &= ~(below | (1ull << f) | ml);
    }
    if (lane == 0) keepw[t] = kw;
    if (seg == 0)      kh0 = (lane == owner) ? kw : kh0;
    else if (seg == 1) kh1 = (lane == owner) ? kw : kh1;
    else               kh2 = (lane == owner) ? kw : kh2;

    // ---- diag prefetch for t+1 (issued early: hides under OR phase)
    if (t + 1 < VB) {
      int rn = (t + 1) * 64 + lane;
      rn = (rn < N_ANCH) ? rn : (N_ANCH - 1);
      mw_pref = mask[(u64)rn * CBLK + (t + 1)];
    }

    bool cons = (t < VB - 1);
    int c = t + 1 + (int)((u32)(lane - (t + 1)) & 63u);  // target column
    u64 acc = 0;

    // scalarized keep word for tier A
    u32 kwlo = (u32)__builtin_amdgcn_readfirstlane((int)(u32)kw);
    u32 kwhi = (u32)__builtin_amdgcn_readfirstlane((int)(u32)(kw >> 32));
    u64 kws = ((u64)kwhi << 32) | kwlo;

    // ---- tier A: consume ping, issue pong for t+1
    if (t & 1) {
      if (cons) acc |= consume_tile(vbuf1, kws);
      if (t + 1 < VB - 1) issue_tile(vbuf0, t + 1);
    } else {
      if (cons) acc |= consume_tile(vbuf0, kws);
      if (t + 1 < VB - 1) issue_tile(vbuf1, t + 1);
    }

    // ---- tier B: block t-64 (slow path, fires on few iterations)
    if (t >= 64 && cons) {
      int bb = t - 64;
      u64 kwB = readlane_u64((bb >= 64) ? kh1 : kh0, bb & 63);
      int cc = (c < CBLK) ? c : (CBLK - 1);
      const u64* bp = mask + (u64)(bb * 64) * CBLK + cc;
      #pragma unroll
      for (int ch = 0; ch < 8; ++ch) {
        u32 byte = (u32)((kwB >> (ch * 8)) & 0xffull);
        if (byte) {                              // uniform skip
          u64 w[8];
          #pragma unroll
          for (int j = 0; j < 8; ++j) w[j] = bp[(u64)(ch * 8 + j) * CBLK];
          #pragma unroll
          for (int j = 0; j < 8; ++j) {
            u64 sm = (u64)0 - ((kwB >> (ch * 8 + j)) & 1ull);
            acc |= w[j] & sm;
          }
        }
      }
    }
    // ---- tier C: block t-128 (only t in [128,131])
    if (t >= 128 && cons) {
      int bb = t - 128;                          // < 64 => kh0
      u64 kwC = readlane_u64(kh0, bb & 63);
      int cc = (c < CBLK) ? c : (CBLK - 1);
      const u64* bp = mask + (u64)(bb * 64) * CBLK + cc;
      #pragma unroll
      for (int ch = 0; ch < 8; ++ch) {
        u32 byte = (u32)((kwC >> (ch * 8)) & 0xffull);
        if (byte) {
          u64 w[8];
          #pragma unroll
          for (int j = 0; j < 8; ++j) w[j] = bp[(u64)(ch * 8 + j) * CBLK];
          #pragma unroll
          for (int j = 0; j < 8; ++j) {
            u64 sm = (u64)0 - ((kwC >> (ch * 8 + j)) & 1ull);
            acc |= w[j] & sm;
          }
        }
      }
    }

    // ---- land acc in-lane (column c owned by this lane)
    if (cons && c < VB) {
      int cs = c >> 6;
      if (cs == 0)      rem0 |= acc;
      else if (cs == 1) rem1 |= acc;
      else              rem2 |= acc;
    }
  }
  __syncthreads();

  // ---- fused masked output
  for (int r2 = lane; r2 < N_ANCH; r2 += 64) {
    u64 kv = keepw[r2 >> 6];
    bool kp = (kv >> (r2 & 63)) & 1ull;
    float4 b4 = sbox[r2];
    float sc = sscore[r2];
    float* o = out + r2 * 5;
    o[0] = kp ? b4.x : 0.f;
    o[1] = kp ? b4.y : 0.f;
    o[2] = kp ? b4.z : 0.f;
    o[3] = kp ? b4.w : 0.f;
    o[4] = kp ? sc : 0.f;
  }
}

extern "C" void kernel_launch(void* const* d_in, const int* in_sizes, int n_in,
                              void* d_out, int out_size, void* d_ws, size_t ws_size,
                              hipStream_t stream) {
  const float* raw = (const float*)d_in[0];
  float* out = (float*)d_out;
  char* ws = (char*)d_ws;
  // ws layout: sbox (8448*16 B) | sscore (8448*4 B) | mask (8400*132*8 B) ≈ 9.04 MB
  float4* sbox = (float4*)ws;
  float* sscore = (float*)(ws + 8448 * 16);
  u64* mask = (u64*)(ws + 8448 * 16 + 8448 * 4);

  rank_kernel<<<2100, 256, 0, stream>>>(raw, sbox, sscore);
  mask_kernel<<<dim3(CBLK, 33), 256, 0, stream>>>(sbox, sscore, mask);
  nms_kernel<<<1, 64, 0, stream>>>(sbox, sscore, mask, out);
}

// Round 8
// 176.038 us; speedup vs baseline: 1.7416x; 1.5284x over previous
//
#include <hip/hip_runtime.h>
#include <cstdint>

#define N_ANCH 8400
#define CBLK 132              // ceil(8400/64)
#define SCORE_THR 0.5f

typedef unsigned long long u64;
typedef unsigned int u32;

// Sort key: ascending sort == (valid score descending, then index ascending,
// invalid last by index ascending) — exactly matches
// argsort(-where(valid, s, -inf)) with stable ties.
__device__ __forceinline__ u64 sort_key(float s, int idx) {
  u32 k32 = (s >= SCORE_THR) ? ~__float_as_uint(s) : 0xFFFFFFFFu;
  return ((u64)k32 << 32) | (u32)idx;
}

__device__ __forceinline__ u64 readlane_u64(u64 v, int l) {
  u32 rlo = (u32)__builtin_amdgcn_readlane((int)(u32)v, l);
  u32 rhi = (u32)__builtin_amdgcn_readlane((int)(u32)(v >> 32), l);
  return ((u64)rhi << 32) | rlo;
}

// One 64-lane wave per anchor: rank = #{keys smaller}, then scatter
// decoded box + score into sorted position.
__global__ void __launch_bounds__(256) rank_kernel(const float* __restrict__ raw,
                                                   float4* __restrict__ sbox,
                                                   float* __restrict__ sscore) {
  #pragma clang fp contract(off)
  int tid = blockIdx.x * 256 + threadIdx.x;
  int row = tid >> 6, lane = tid & 63;
  if (row >= N_ANCH) return;
  float si = raw[4 * N_ANCH + row];
  u64 ki = sort_key(si, row);
  int cnt = 0;
  for (int j = lane; j < N_ANCH; j += 64) {
    float sj = raw[4 * N_ANCH + j];
    cnt += (sort_key(sj, j) < ki) ? 1 : 0;
  }
  #pragma unroll
  for (int d = 1; d < 64; d <<= 1) cnt += __shfl_xor(cnt, d, 64);
  if (lane == 0) {
    float cx = raw[row], cy = raw[N_ANCH + row];
    float w = raw[2 * N_ANCH + row], h = raw[3 * N_ANCH + row];
    float hw = w * 0.5f, hh = h * 0.5f;
    sbox[cnt] = make_float4(cx - hw, cy - hh, cx + hw, cy + hh);
    sscore[cnt] = si;
  }
}

// Suppression bitmask over sorted boxes. 256 threads = 256 rows x 64 cols
// per block; grid (CBLK, 33). mask[i*CBLK+cb] bit jj set iff j=cb*64+jj has
// j>i, j<N, iou(i,j) > 0.5. Skips tiles below the diagonal and tiles with
// all-invalid rows/cols (validity is a prefix in sorted order).
__global__ void __launch_bounds__(256) mask_kernel(const float4* __restrict__ sbox,
                                                   const float* __restrict__ sscore,
                                                   u64* __restrict__ mask) {
  #pragma clang fp contract(off)
  int cb = blockIdx.x;
  int i0 = blockIdx.y * 256;
  if (cb * 64 + 63 < i0) return;
  if (!(sscore[i0] >= SCORE_THR)) return;
  if (!(sscore[cb * 64] >= SCORE_THR)) return;
  int t = threadIdx.x;
  __shared__ float4 cbox[64];
  __shared__ float carea[64];
  int j0 = cb * 64;
  if (t < 64) {
    int j = j0 + t;
    float4 bj = (j < N_ANCH) ? sbox[j] : make_float4(0.f, 0.f, 0.f, 0.f);
    cbox[t] = bj;
    carea[t] = (bj.z - bj.x) * (bj.w - bj.y);
  }
  __syncthreads();
  int i = i0 + t;
  if (i >= N_ANCH || i >= (cb + 1) * 64) return;
  float4 bi = sbox[i];
  float ai = (bi.z - bi.x) * (bi.w - bi.y);
  u64 word = 0;
  for (int jj = 0; jj < 64; ++jj) {
    int jg = j0 + jj;
    if (jg <= i || jg >= N_ANCH) continue;
    float4 bb = cbox[jj];
    float ltx = fmaxf(bi.x, bb.x), lty = fmaxf(bi.y, bb.y);
    float rbx = fminf(bi.z, bb.z), rby = fminf(bi.w, bb.w);
    float wx = fmaxf(rbx - ltx, 0.f), wy = fmaxf(rby - lty, 0.f);
    float inter = wx * wy;
    float uni = (ai + carea[jj]) - inter;      // same op order as reference
    float iou = inter / fmaxf(uni, 1e-9f);     // IEEE div, matches numpy
    if (iou > 0.5f) word |= (1ull << jj);
  }
  mask[(u64)i * CBLK + cb] = word;
}

// 512 threads = 8 waves = (2 col-sets s) x (4 row-quarters q).
// Iteration t: wave (s,q) applies rows 16q..16q+15 of block t to columns
// t+1+64s+lane (predicated to c<VB => loads skipped for OOB lanes). Columns
// [t+1,t+128] covered every iteration; rare third window [t+129,t+192] for
// worst-case VB (<=132 <=192 => provably complete). Per-wave tile = 16 u64
// (32 VGPRs, resident). removed = 4 quarter-partial LDS arrays (exclusive
// (q,c) cells, no atomics). Barrier drains LDS ONLY — prefetched global
// loads stay in flight across it. Scan runs redundantly in all 8 waves.
__global__ void __launch_bounds__(512, 1) nms_kernel(const float4* __restrict__ sbox,
                                                     const float* __restrict__ sscore,
                                                     const u64* __restrict__ mask,
                                                     float* __restrict__ out) {
  __shared__ u64 keepw[CBLK];
  __shared__ u64 rem4[4][CBLK];
  int tid = threadIdx.x;
  int wave = tid >> 6, lane = tid & 63;
  int s = wave >> 2, q = wave & 3;

  // ---- n_valid via 2-round probe (redundant in every wave — same result)
  float s0 = sscore[lane * 132];                 // 63*132 = 8316 < 8400
  u64 b0 = __ballot(s0 >= SCORE_THR);
  int cnt1 = (int)__popcll(b0);
  int n_valid = 0;
  if (cnt1 > 0) {
    int a = (cnt1 - 1) * 132 + 1;                // rows < a known valid
    int i1 = a + 3 * lane;
    float t1 = (i1 + 0 < N_ANCH) ? sscore[i1 + 0] : -1.f;
    float t2 = (i1 + 1 < N_ANCH) ? sscore[i1 + 1] : -1.f;
    float t3 = (i1 + 2 < N_ANCH) ? sscore[i1 + 2] : -1.f;
    u64 q1 = __ballot(t1 >= SCORE_THR);
    u64 q2 = __ballot(t2 >= SCORE_THR);
    u64 q3 = __ballot(t3 >= SCORE_THR);
    n_valid = a + (int)__popcll(q1) + (int)__popcll(q2) + (int)__popcll(q3);
  }
  int VB = (n_valid + 63) >> 6;                  // number of valid 64-blocks

  for (int b = tid; b < CBLK; b += 512) keepw[b] = 0;
  for (int x = tid; x < 4 * CBLK; x += 512) ((u64*)rem4)[x] = 0;

  u64 v[16];                                     // per-wave tile (32 VGPRs)
  auto issue_tile = [&](int tt) {                // tile consumed at iter tt
    int c = tt + 1 + 64 * s + lane;
    bool ok = (c < VB);
    const u64* bp = mask + (u64)(tt * 64 + 16 * q) * CBLK + c;
    #pragma unroll
    for (int i = 0; i < 16; ++i) v[i] = ok ? bp[(u64)i * CBLK] : 0ull;
  };

  // prologue: diag words + tile for t=0
  u64 mw_pref = 0;
  if (VB > 0) {
    mw_pref = mask[(u64)lane * CBLK];
    if (VB >= 2) issue_tile(0);
  }

  for (int t = 0; t < VB; ++t) {
    // LDS-only drain + barrier: global prefetches stay in flight
    asm volatile("s_waitcnt lgkmcnt(0)\ns_barrier" ::: "memory");

    u64 remb = rem4[0][t] | rem4[1][t] | rem4[2][t] | rem4[3][t];
    int remn = n_valid - t * 64;                 // >= 1
    u64 vmask = (remn >= 64) ? ~0ull : ((1ull << remn) - 1ull);
    u64 act = vmask & ~remb;

    // ---- scan (ballot fast path; redundant & identical in all waves)
    u64 mw = mw_pref;
    u64 sup = __ballot((((act >> lane) & 1ull) != 0ull) && (mw != 0ull));
    u64 a = act, kw = 0;
    while (a) {
      u64 as = a & sup;
      if (as == 0ull) { kw |= a; break; }
      int f = (int)__builtin_ctzll(as);
      u64 below = a & ((1ull << f) - 1ull);
      kw |= below | (1ull << f);
      u64 ml = readlane_u64(mw, f);
      a &= ~(below | (1ull << f) | ml);
    }
    if (tid == 0) keepw[t] = kw;

    // scalarized keep word
    u32 kwlo = (u32)__builtin_amdgcn_readfirstlane((int)(u32)kw);
    u32 kwhi = (u32)__builtin_amdgcn_readfirstlane((int)(u32)(kw >> 32));
    u64 kws = ((u64)kwhi << 32) | kwlo;

    // ---- consume tile (loads issued last iteration): masked OR + LDS RMW
    if (t < VB - 1) {
      u64 acc = 0;
      #pragma unroll
      for (int i = 0; i < 16; ++i) {
        u64 sm = (u64)0 - ((kws >> (16 * q + i)) & 1ull);
        acc |= v[i] & sm;
      }
      int c = t + 1 + 64 * s + lane;
      if (c < VB) rem4[q][c] |= acc;             // exclusive (q,c) cell
    }

    // ---- prefetch diag for t+1, issue tile for t+1
    if (t + 1 < VB) {
      int rn = (t + 1) * 64 + lane;
      rn = (rn < N_ANCH) ? rn : (N_ANCH - 1);
      mw_pref = mask[(u64)rn * CBLK + (t + 1)];
      if (t + 1 < VB - 1) issue_tile(t + 1);
    }

    // ---- rare far window [t+129, t+192) — only when VB > t+129 (<=3 iters
    // even at worst-case VB=132; never fires at VB~66)
    if (t + 129 < VB && s == 1) {
      int c2 = t + 129 + lane;
      if (c2 < VB) {
        const u64* bp = mask + (u64)(t * 64 + 16 * q) * CBLK + c2;
        u64 acc2 = 0;
        #pragma unroll
        for (int i = 0; i < 16; ++i) {
          u64 sm = (u64)0 - ((kws >> (16 * q + i)) & 1ull);
          acc2 |= bp[(u64)i * CBLK] & sm;
        }
        rem4[q][c2] |= acc2;                     // disjoint from c (>t+128)
      }
    }
  }
  __syncthreads();

  // ---- fused masked output (512 threads)
  for (int r2 = tid; r2 < N_ANCH; r2 += 512) {
    u64 kv = keepw[r2 >> 6];
    bool kp = (kv >> (r2 & 63)) & 1ull;
    float4 b4 = sbox[r2];
    float sc = sscore[r2];
    float* o = out + r2 * 5;
    o[0] = kp ? b4.x : 0.f;
    o[1] = kp ? b4.y : 0.f;
    o[2] = kp ? b4.z : 0.f;
    o[3] = kp ? b4.w : 0.f;
    o[4] = kp ? sc : 0.f;
  }
}

extern "C" void kernel_launch(void* const* d_in, const int* in_sizes, int n_in,
                              void* d_out, int out_size, void* d_ws, size_t ws_size,
                              hipStream_t stream) {
  const float* raw = (const float*)d_in[0];
  float* out = (float*)d_out;
  char* ws = (char*)d_ws;
  // ws layout: sbox (8448*16 B) | sscore (8448*4 B) | mask (8400*132*8 B) ≈ 9.04 MB
  float4* sbox = (float4*)ws;
  float* sscore = (float*)(ws + 8448 * 16);
  u64* mask = (u64*)(ws + 8448 * 16 + 8448 * 4);

  rank_kernel<<<2100, 256, 0, stream>>>(raw, sbox, sscore);
  mask_kernel<<<dim3(CBLK, 33), 256, 0, stream>>>(sbox, sscore, mask);
  nms_kernel<<<1, 512, 0, stream>>>(sbox, sscore, mask, out);
}